// Round 7
// baseline (336.940 us; speedup 1.0000x reference)
//
#include <hip/hip_runtime.h>

typedef unsigned short u16;
typedef unsigned int u32;
typedef __attribute__((ext_vector_type(8))) __bf16 bh8;
typedef __attribute__((ext_vector_type(4))) float fx4;

#define AS1 __attribute__((address_space(1)))
#define AS3 __attribute__((address_space(3)))

__device__ __forceinline__ void gll16(const void* g, void* l) {
  void* gg = const_cast<void*>(g);
  __builtin_amdgcn_global_load_lds((AS1 void*)gg, (AS3 void*)l, 16, 0, 0);
}

__device__ __forceinline__ u16 f2b(float f) {
  union { float f; u32 u; } v; v.f = f;
  u32 r = v.u + 0x7FFFu + ((v.u >> 16) & 1u);
  return (u16)(r >> 16);
}

__device__ __forceinline__ fx4 fzero() { fx4 z = {0.f, 0.f, 0.f, 0.f}; return z; }

#define MFMA16(a, b, c) __builtin_amdgcn_mfma_f32_16x16x32_bf16(a, b, c, 0, 0, 0)
#define SBAR() asm volatile("s_barrier" ::: "memory")
#define VMCNT2() asm volatile("s_waitcnt vmcnt(2)" ::: "memory")
#define VMCNT0() asm volatile("s_waitcnt vmcnt(0)" ::: "memory")

// ---------------- cast f32 -> bf16, vectorized ----------------
__global__ void k_cast(const float* __restrict__ in, u16* __restrict__ out, int n4) {
  int i = blockIdx.x * blockDim.x + threadIdx.x;
  if (i >= n4) return;
  float4 v = reinterpret_cast<const float4*>(in)[i];
  ushort4 o;
  o.x = f2b(v.x); o.y = f2b(v.y); o.z = f2b(v.z); o.w = f2b(v.w);
  reinterpret_cast<ushort4*>(out)[i] = o;
}

// ---------------- transpose + cast: W[R][C] f32 -> Wt[C][R] bf16 ----------------
__global__ void k_transpose_cast(const float* __restrict__ in, u16* __restrict__ out,
                                 int R, int C) {
  __shared__ float t[32][33];
  int tx = threadIdx.x, ty = threadIdx.y;
  int r0 = blockIdx.y * 32, c0 = blockIdx.x * 32;
#pragma unroll
  for (int j = 0; j < 4; j++)
    t[ty + 8 * j][tx] = in[(size_t)(r0 + ty + 8 * j) * C + c0 + tx];
  __syncthreads();
#pragma unroll
  for (int j = 0; j < 4; j++)
    out[(size_t)(c0 + ty + 8 * j) * R + r0 + tx] = f2b(t[tx][ty + 8 * j]);
}

// ---------------- transpose V (bf16): [(b*2048+s)*512 + kv*128 + d] -> [(z*128+d)*2048 + s]
__global__ void k_transpose_v(const u16* __restrict__ in, u16* __restrict__ out) {
  __shared__ u16 t[32][33];
  int tx = threadIdx.x, ty = threadIdx.y;
  int s0 = blockIdx.x * 32, d0 = blockIdx.y * 32;
  int z = blockIdx.z, b = z >> 2, kv = z & 3;
#pragma unroll
  for (int j = 0; j < 4; j++)
    t[ty + 8 * j][tx] = in[(size_t)(b * 2048 + s0 + ty + 8 * j) * 512 + kv * 128 + d0 + tx];
  __syncthreads();
#pragma unroll
  for (int j = 0; j < 4; j++)
    out[(size_t)(z * 128 + d0 + ty + 8 * j) * 2048 + s0 + tx] = t[tx][ty + 8 * j];
}

// ---------------- 256x256 GEMM core, counted-vmcnt pipeline (T3+T4) -------
// 8 waves (2M x 4N), BK=64, LDS 128KB: A[2][256x64] + B[2][256x64], linear
// dest + granule-XOR swizzle via pre-swizzled global source (rule #21).
// Per K-tile: 4 phases {ds_read frags; issue 2 gll16 (chunk p of tile t+1 ->
// other buf); s_barrier; 16 MFMA (setprio); s_barrier}. Tile switch waits
// vmcnt(2) (8 old loads drained, 2 fresh kept) -- never vmcnt(0) mid-loop.
__device__ __forceinline__ void gemm256(const u16* __restrict__ A, const u16* __restrict__ Bt,
                                        int bm, int bn, u16* Sm, fx4 (&acc)[8][4]) {
  u16* As0 = Sm;          u16* As1 = Sm + 16384;
  u16* Bs0 = Sm + 32768;  u16* Bs1 = Sm + 49152;
  const int tid = threadIdx.x, lane = tid & 63;
  const int i = lane & 15, g = lane >> 4;
  const int w = tid >> 6, wr = w >> 2, wc = w & 3;
  const int arow0 = wr * 128 + i;
  const int brow0 = wc * 64 + i;
  const int swz = i & 7;
  const int srow = tid >> 3;                 // 0..63 within a 64-row chunk
  const int lg = (tid & 7) ^ (srow & 7);     // pre-swizzled source granule
  const size_t aoff = (size_t)(bm + srow) * 2048 + lg * 8;
  const size_t boff = (size_t)(bn + srow) * 2048 + lg * 8;
  const int dslot = tid * 8;

  auto CHUNK = [&](int c, int ktn, u16* nA, u16* nB) {
    gll16(A + aoff + (size_t)c * 64 * 2048 + ktn, nA + c * 4096 + dslot);
    gll16(Bt + boff + (size_t)c * 64 * 2048 + ktn, nB + c * 4096 + dslot);
  };

  auto ITER = [&](const u16* cA, const u16* cB, u16* nA, u16* nB, int ktn, bool stage) {
    // ---- phase 0: tile switch ----
    if (stage) { CHUNK(0, ktn, nA, nB); VMCNT2(); }
    else       { VMCNT0(); }
    SBAR();
    __builtin_amdgcn_sched_barrier(0);
    bh8 bf[4][2];
#pragma unroll
    for (int nf = 0; nf < 4; nf++)
#pragma unroll
      for (int kk = 0; kk < 2; kk++)
        bf[nf][kk] = *reinterpret_cast<const bh8*>(
            cB + (brow0 + nf * 16) * 64 + (((kk * 4 + g) ^ swz) << 3));
    {
      bh8 af[2][2];
#pragma unroll
      for (int mm = 0; mm < 2; mm++)
#pragma unroll
        for (int kk = 0; kk < 2; kk++)
          af[mm][kk] = *reinterpret_cast<const bh8*>(
              cA + (arow0 + mm * 16) * 64 + (((kk * 4 + g) ^ swz) << 3));
      __builtin_amdgcn_s_setprio(1);
#pragma unroll
      for (int mm = 0; mm < 2; mm++)
#pragma unroll
        for (int nf = 0; nf < 4; nf++)
#pragma unroll
          for (int kk = 0; kk < 2; kk++)
            acc[mm][nf] = MFMA16(af[mm][kk], bf[nf][kk], acc[mm][nf]);
      __builtin_amdgcn_s_setprio(0);
    }
    SBAR();
    // ---- phases 1..3 ----
#pragma unroll
    for (int mp = 1; mp < 4; mp++) {
      bh8 af[2][2];
#pragma unroll
      for (int mm = 0; mm < 2; mm++)
#pragma unroll
        for (int kk = 0; kk < 2; kk++)
          af[mm][kk] = *reinterpret_cast<const bh8*>(
              cA + (arow0 + (mp * 2 + mm) * 16) * 64 + (((kk * 4 + g) ^ swz) << 3));
      if (stage) CHUNK(mp, ktn, nA, nB);
      SBAR();
      __builtin_amdgcn_s_setprio(1);
#pragma unroll
      for (int mm = 0; mm < 2; mm++)
#pragma unroll
        for (int nf = 0; nf < 4; nf++)
#pragma unroll
          for (int kk = 0; kk < 2; kk++)
            acc[mp * 2 + mm][nf] = MFMA16(af[mm][kk], bf[nf][kk], acc[mp * 2 + mm][nf]);
      __builtin_amdgcn_s_setprio(0);
      SBAR();
    }
  };

  // prologue: stage tile 0 fully, drain, barrier
#pragma unroll
  for (int c = 0; c < 4; c++) CHUNK(c, 0, As0, Bs0);
  VMCNT0();
  SBAR();
  // 32 K-tiles; invariant: 8 loads (next tile) outstanding at each switch
  for (int t = 0; t < 32; t += 2) {
    ITER(As0, Bs0, As1, Bs1, (t + 1) * 64, true);
    ITER(As1, Bs1, As0, Bs0, (t + 2) * 64, t + 2 < 32);
  }
}

// ---------------- fused QKV projection GEMM (256x256 tiles) ----------------
// Wt = concatenated [3072][2048] (Wq^T rows 0-2047, Wk^T 2048-2559, Wv^T 2560-3071).
__global__ __launch_bounds__(512, 2) void k_proj(const u16* __restrict__ xb,
                                                 const u16* __restrict__ Wt,
                                                 u16* __restrict__ Qb, u16* __restrict__ Kb,
                                                 u16* __restrict__ Vb) {
  __shared__ __align__(16) u16 Sm[65536];
  fx4 acc[8][4];
#pragma unroll
  for (int m = 0; m < 8; m++)
#pragma unroll
    for (int n = 0; n < 4; n++) acc[m][n] = fzero();
  const int bm = blockIdx.x * 256, by = blockIdx.y, bn = by * 256;
  gemm256(xb, Wt, bm, bn, Sm, acc);

  u16* Cp; int coff, ldc; float alpha;
  if (by < 8)       { Cp = Qb; coff = by * 256;        ldc = 2048; alpha = 0.08838834764831845f; }
  else if (by < 10) { Cp = Kb; coff = (by - 8) * 256;  ldc = 512;  alpha = 1.0f; }
  else              { Cp = Vb; coff = (by - 10) * 256; ldc = 512;  alpha = 1.0f; }

  const int lane = threadIdx.x & 63, w = threadIdx.x >> 6;
  const int wr = w >> 2, wc = w & 3, i = lane & 15, g = lane >> 4;
#pragma unroll
  for (int mf = 0; mf < 8; mf++)
#pragma unroll
    for (int nf = 0; nf < 4; nf++)
#pragma unroll
      for (int r = 0; r < 4; r++) {
        int row = bm + wr * 128 + mf * 16 + 4 * g + r;
        int col = coff + wc * 64 + nf * 16 + i;
        Cp[(size_t)row * ldc + col] = f2b(acc[mf][nf][r] * alpha);
      }
}

// ---------------- output GEMM (f32 out, 256x256 tiles) ----------------
__global__ __launch_bounds__(512, 2) void k_gemm_out(const u16* __restrict__ Ob,
                                                     const u16* __restrict__ Wot,
                                                     float* __restrict__ C) {
  __shared__ __align__(16) u16 Sm[65536];
  fx4 acc[8][4];
#pragma unroll
  for (int m = 0; m < 8; m++)
#pragma unroll
    for (int n = 0; n < 4; n++) acc[m][n] = fzero();
  const int bm = blockIdx.x * 256, bn = blockIdx.y * 256;
  gemm256(Ob, Wot, bm, bn, Sm, acc);

  const int lane = threadIdx.x & 63, w = threadIdx.x >> 6;
  const int wr = w >> 2, wc = w & 3, i = lane & 15, g = lane >> 4;
#pragma unroll
  for (int mf = 0; mf < 8; mf++)
#pragma unroll
    for (int nf = 0; nf < 4; nf++)
#pragma unroll
      for (int r = 0; r < 4; r++) {
        int row = bm + wr * 128 + mf * 16 + 4 * g + r;
        int col = bn + wc * 64 + nf * 16 + i;
        C[(size_t)row * 2048 + col] = acc[mf][nf][r];
      }
}

// ---------------- flash attention v5 (causal, GQA) — unchanged ----------------
__global__ __launch_bounds__(512, 4) void k_attn(const u16* __restrict__ Qb,
                                                 const u16* __restrict__ Kb,
                                                 const u16* __restrict__ Vt,
                                                 u16* __restrict__ Ob) {
  __shared__ __align__(16) u16 Ks0[64 * 128], Ks1[64 * 128];
  __shared__ __align__(16) u16 Vs0[128 * 64], Vs1[128 * 64];
  __shared__ __align__(16) u16 Pl[8][16 * 64];
  const int tid = threadIdx.x, lane = tid & 63, w = tid >> 6;
  const int i = lane & 15, g = lane >> 4;
  const int j = blockIdx.x;                 // 0..15
  const int head = blockIdx.y, b = blockIdx.z, kv = head >> 2;
  const bool isA = (w >= 4);                // waves 4-7: early tile j
  const int qt = isA ? j : (31 - j);
  const int qmin = qt * 64 + (w & 3) * 16;  // this wave's 16 q-rows
  const int nt = 32 - j;                    // block iteration count
  const int myNt = isA ? (j + 1) : nt;      // kv-tiles this wave consumes

  const u16* Kbb = Kb + (size_t)b * 2048 * 512 + kv * 128;
  const u16* Vbb = Vt + (size_t)(b * 4 + kv) * 128 * 2048;

  bh8 qf[4];
  {
    const u16* qp = Qb + (size_t)(b * 2048 + qmin + i) * 2048 + head * 128 + g * 8;
#pragma unroll
    for (int kb = 0; kb < 4; kb++) qf[kb] = *reinterpret_cast<const bh8*>(qp + kb * 32);
  }

  fx4 o[8];
#pragma unroll
  for (int dt = 0; dt < 8; dt++) o[dt] = fzero();
  float m[4] = {-1e30f, -1e30f, -1e30f, -1e30f};
  float lp[4] = {0.f, 0.f, 0.f, 0.f};       // per-lane PARTIAL row sums

  auto STAGE = [&](u16* Kd, u16* Vd, int s0) {
#pragma unroll
    for (int cc = 0; cc < 2; cc++) {
      int c = tid + cc * 512;
      gll16(Kbb + (size_t)(s0 + (c >> 4)) * 512 + (((c & 15) ^ ((c >> 4) & 7)) * 8),
            Kd + c * 8);
      gll16(Vbb + (size_t)(c >> 3) * 2048 + s0 + (((c & 7) ^ ((c >> 3) & 7)) * 8),
            Vd + c * 8);
    }
  };

  auto TILE = [&](const u16* Kbuf, const u16* Vbuf, int s0) {
    fx4 sc[4];
    __builtin_amdgcn_s_setprio(1);
#pragma unroll
    for (int st = 0; st < 4; st++) {
      sc[st] = fzero();
#pragma unroll
      for (int kb = 0; kb < 4; kb++) {
        bh8 kf = *reinterpret_cast<const bh8*>(Kbuf + (st * 16 + i) * 128 +
                                               (((kb * 4 + g) ^ (i & 7)) * 8));
        sc[st] = MFMA16(qf[kb], kf, sc[st]);
      }
    }
    __builtin_amdgcn_s_setprio(0);
    if (s0 + 63 > qmin) {
#pragma unroll
      for (int st = 0; st < 4; st++)
#pragma unroll
        for (int r = 0; r < 4; r++) {
          int s = s0 + st * 16 + i;
          int q = qmin + 4 * g + r;
          if (s > q) sc[st][r] = -1e30f;
        }
    }
    float pmax[4];
#pragma unroll
    for (int r = 0; r < 4; r++) {
      float v = fmaxf(fmaxf(sc[0][r], sc[1][r]), fmaxf(sc[2][r], sc[3][r]));
      v = fmaxf(v, __shfl_xor(v, 1));
      v = fmaxf(v, __shfl_xor(v, 2));
      v = fmaxf(v, __shfl_xor(v, 4));
      v = fmaxf(v, __shfl_xor(v, 8));
      pmax[r] = v;
    }
    int need = 0;
#pragma unroll
    for (int r = 0; r < 4; r++) need |= (pmax[r] > m[r] + 8.0f) ? 1 : 0;
    if (__any(need)) {
#pragma unroll
      for (int r = 0; r < 4; r++) {
        float mn = fmaxf(m[r], pmax[r]);
        float corr = __expf(m[r] - mn);
        m[r] = mn;
        lp[r] *= corr;
#pragma unroll
        for (int dt = 0; dt < 8; dt++) o[dt][r] *= corr;
      }
    }
    float p[4][4];
#pragma unroll
    for (int r = 0; r < 4; r++) {
#pragma unroll
      for (int st = 0; st < 4; st++) p[st][r] = __expf(sc[st][r] - m[r]);
      lp[r] += (p[0][r] + p[1][r]) + (p[2][r] + p[3][r]);
    }

#pragma unroll
    for (int st = 0; st < 4; st++)
#pragma unroll
      for (int r = 0; r < 4; r++) {
        int row = 4 * g + r;
        int cg = st * 2 + (i >> 3);
        Pl[w][row * 64 + ((cg ^ (row & 7)) << 3) + (i & 7)] = f2b(p[st][r]);
      }
    bh8 pf0 = *reinterpret_cast<const bh8*>(&Pl[w][i * 64 + ((g ^ (i & 7)) << 3)]);
    bh8 pf1 = *reinterpret_cast<const bh8*>(&Pl[w][i * 64 + (((4 + g) ^ (i & 7)) << 3)]);
    __builtin_amdgcn_s_setprio(1);
#pragma unroll
    for (int dt = 0; dt < 8; dt++) {
      bh8 v0 = *reinterpret_cast<const bh8*>(Vbuf + (dt * 16 + i) * 64 +
                                             ((g ^ (i & 7)) * 8));
      bh8 v1 = *reinterpret_cast<const bh8*>(Vbuf + (dt * 16 + i) * 64 +
                                             (((4 + g) ^ (i & 7)) * 8));
      o[dt] = MFMA16(pf0, v0, o[dt]);
      o[dt] = MFMA16(pf1, v1, o[dt]);
    }
    __builtin_amdgcn_s_setprio(0);
  };

  STAGE(Ks0, Vs0, 0);
  __syncthreads();
  for (int t = 0; t < nt; t += 2) {
    if (t + 1 < nt) STAGE(Ks1, Vs1, (t + 1) * 64);
    if (t < myNt) TILE(Ks0, Vs0, t * 64);
    __syncthreads();
    if (t + 1 >= nt) break;
    if (t + 2 < nt) STAGE(Ks0, Vs0, (t + 2) * 64);
    if (t + 1 < myNt) TILE(Ks1, Vs1, (t + 1) * 64);
    __syncthreads();
  }

#pragma unroll
  for (int r = 0; r < 4; r++) {
    float s = lp[r];
    s += __shfl_xor(s, 1);
    s += __shfl_xor(s, 2);
    s += __shfl_xor(s, 4);
    s += __shfl_xor(s, 8);
    float inv = 1.0f / s;
#pragma unroll
    for (int dt = 0; dt < 8; dt++)
      Ob[(size_t)(b * 2048 + qmin + 4 * g + r) * 2048 + head * 128 + dt * 16 + i] =
          f2b(o[dt][r] * inv);
  }
}

extern "C" void kernel_launch(void* const* d_in, const int* in_sizes, int n_in,
                              void* d_out, int out_size, void* d_ws, size_t ws_size,
                              hipStream_t stream) {
  (void)in_sizes; (void)n_in; (void)out_size; (void)ws_size;
  const float* x  = (const float*)d_in[0];
  const float* Wq = (const float*)d_in[1];
  const float* Wk = (const float*)d_in[2];
  const float* Wv = (const float*)d_in[3];
  const float* Wo = (const float*)d_in[4];

  char* ws = (char*)d_ws;
  size_t off = 0;
  auto alloc = [&](size_t bytes) {
    void* p = ws + off;
    off += (bytes + 255) & ~(size_t)255;
    return p;
  };
  u16* xb  = (u16*)alloc(8388608ull * 2);  // x bf16; reused as Ob after proj
  u16* Wqt = (u16*)alloc(4194304ull * 2);  // rows 0-2047 of concat Wt
  u16* Wkt = (u16*)alloc(1048576ull * 2);  // rows 2048-2559 (contiguous)
  u16* Wvt = (u16*)alloc(1048576ull * 2);  // rows 2560-3071 (contiguous)
  u16* Wot = (u16*)alloc(4194304ull * 2);
  u16* Qb  = (u16*)alloc(8388608ull * 2);
  u16* Kb  = (u16*)alloc(2097152ull * 2);
  u16* Vb  = (u16*)alloc(2097152ull * 2);
  u16* Vt  = (u16*)alloc(2097152ull * 2);
  u16* Ob  = xb;  // x is dead after k_proj

  k_cast<<<8192, 256, 0, stream>>>(x, xb, 2097152);
  k_transpose_cast<<<dim3(64, 64), dim3(32, 8), 0, stream>>>(Wq, Wqt, 2048, 2048);
  k_transpose_cast<<<dim3(16, 64), dim3(32, 8), 0, stream>>>(Wk, Wkt, 2048, 512);
  k_transpose_cast<<<dim3(16, 64), dim3(32, 8), 0, stream>>>(Wv, Wvt, 2048, 512);
  k_transpose_cast<<<dim3(64, 64), dim3(32, 8), 0, stream>>>(Wo, Wot, 2048, 2048);
  k_proj<<<dim3(16, 12), 512, 0, stream>>>(xb, Wqt, Qb, Kb, Vb);
  k_transpose_v<<<dim3(64, 4, 8), dim3(32, 8), 0, stream>>>(Vb, Vt);
  k_attn<<<dim3(16, 16, 2), 512, 0, stream>>>(Qb, Kb, Vt, Ob);
  k_gemm_out<<<dim3(16, 8), 512, 0, stream>>>(Ob, Wot, (float*)d_out);
}